// Round 8
// baseline (221.949 us; speedup 1.0000x reference)
//
#include <hip/hip_runtime.h>
#include <math.h>

#define NB    16        // batch
#define NC    25        // channels
#define HW    65536     // 256*256
#define CHW   (NC * HW)
#define EPSF  1e-8f
#define TPB   256       // 4 waves, 1 px per thread
#define PXB   256       // pixels per block
#define NBLK  (NB * (HW / PXB))   // 4096 blocks
#define NSTR  64        // accumulator stripes (parallel atomic chains)
#define SACC  64        // floats per stripe

__device__ __forceinline__ float wave_reduce(float v) {
#pragma unroll
    for (int o = 32; o > 0; o >>= 1) v += __shfl_down(v, o, 64);
    return v;
}

// R15 == R14 resubmitted (R14's bench died in container acquisition; the
// kernel was never compiled/run -- do not mutate an unmeasured kernel).
// R14: 1 px/thread, 50 scalar loads pinned live via asm keep-alive.
// R13 post-mortem: striping the atomics fixed the serial RMW chain (318->75us
// at 4096 blocks; warm dispatches now FASTER than cold -- predicted
// inversion). But VGPR stayed 32 (< the 40 the ten float4 payloads need), so
// loads were still serialized into their consumers: sched_barrier(0) failed
// TWICE because the sinking happens at LLVM IR level (into the divergent
// branch bodies), before the machine scheduler ever sees the fence.
// Fix: (a) no branches -- every thread does identical work on its own pixel
// (kills the sink destination, the LDS partials, the mid-kernel barrier,
// the wave-0 tail, and the bank conflicts); (b) pin all 50 loaded values
// with asm volatile("" :: "v"(x)) (guide rule #17): a DATA DEPENDENCY
// cannot be sunk past by any pass. 50 coalesced dword loads issued
// back-to-back = ~12.8KB in flight/wave x ~20 waves/CU -- memcpy-shaped.
// Floor: 210MB touched, ~half HBM-cold -> ~30-35us.
__global__ __launch_bounds__(TPB) void yolo_main(const float* __restrict__ outputs,
                                                 const float* __restrict__ labels,
                                                 float* __restrict__ acc) {
    const int wv   = threadIdx.x >> 6;
    const int lane = threadIdx.x & 63;
    const int b    = blockIdx.x >> 8;                      // image
    const int px   = ((blockIdx.x & 255) << 8) + threadIdx.x;
    const size_t base = (size_t)b * CHW + px;
    const float* op = outputs + base;
    const float* lp = labels  + base;

    // ---- 50 independent coalesced dword loads: the thread's entire input
    float o[NC], l[NC];
#pragma unroll
    for (int c = 0; c < NC; ++c) o[c] = op[(size_t)c * HW];
#pragma unroll
    for (int c = 0; c < NC; ++c) l[c] = lp[(size_t)c * HW];
    // keep-alive: all 50 values must be live HERE -> no pass can re-sink the
    // loads into the consumption chain below (data dependency, not a fence)
#pragma unroll
    for (int c = 0; c < NC; ++c) asm volatile("" :: "v"(o[c]), "v"(l[c]));

    // ---- channel 0: BCE + F1 counters
    const float xv = o[0], yv = l[0];
    float xc = fminf(fmaxf(xv,        EPSF), 1.0f - EPSF);
    float x1 = fminf(fmaxf(1.0f - xv, EPSF), 1.0f - EPSF);
    float obj = -yv * (1.0f - xc) * __logf(xc)
                - (1.0f - yv) * (1.0f - x1) * __logf(x1);
    const float p  = (xv > 0.5f) ? 1.f : 0.f;
    const float yt = (yv > 0.5f) ? 1.f : 0.f;
    float tp = p * yt;
    float fp = p * (1.f - yt);
    float fn = (1.f - p) * yt;

    // ---- channels 1..4: size / offset L1 (weighted by y)
    float szs  = yv * (fabsf(o[1] - l[1]) + fabsf(o[2] - l[2]));
    float offs = yv * (fabsf(o[3] - l[3]) + fabsf(o[4] - l[4]));

    // ---- channels 5..24: argmax(labels) carrying outputs
    // ascending c + strict '>' = argmax first-index tie-break
    float vmax = -1.0f, vout = 0.0f;
#pragma unroll
    for (int c = 5; c < NC; ++c) {
        if (l[c] > vmax) { vmax = l[c]; vout = o[c]; }
    }
    float cls = yv * (-vout);

    // ---- block reduction: 7 values
    obj  = wave_reduce(obj);
    szs  = wave_reduce(szs);
    offs = wave_reduce(offs);
    cls  = wave_reduce(cls);
    tp   = wave_reduce(tp);
    fp   = wave_reduce(fp);
    fn   = wave_reduce(fn);

    __shared__ float sm[TPB / 64][7];
    if (lane == 0) {
        sm[wv][0] = obj;  sm[wv][1] = szs; sm[wv][2] = offs;
        sm[wv][3] = cls;  sm[wv][4] = tp;  sm[wv][5] = fp;  sm[wv][6] = fn;
    }
    __syncthreads();
    if (threadIdx.x < 7) {
        float s = 0.f;
#pragma unroll
        for (int w = 0; w < TPB / 64; ++w) s += sm[w][threadIdx.x];
        // striped accumulators: 64 parallel short atomic chains
        float* st = acc + (size_t)(blockIdx.x & (NSTR - 1)) * SACC;
        if (threadIdx.x < 4) atomicAdd(st + threadIdx.x, s);
        else                 atomicAdd(st + 4 + 3 * b + (threadIdx.x - 4), s);
    }
}

__global__ void yolo_fin(const float* __restrict__ acc, float* __restrict__ out) {
    const int t = threadIdx.x;                // 64 threads, 1 wave
    __shared__ float fin[52];
    if (t < 52) {
        float s = 0.f;
#pragma unroll
        for (int st = 0; st < NSTR; ++st) s += acc[st * SACC + t];
        fin[t] = s;
    }
    __syncthreads();
    if (t == 0) {
        float objT = fin[0];
        float szT  = 0.1f * fin[1];
        float offT = 0.1f * fin[2];
        float clsT = fin[3];
        float f1 = 0.f;
        for (int bb = 0; bb < NB; ++bb) {
            float tpv = fin[4 + 3 * bb], fpv = fin[5 + 3 * bb], fnv = fin[6 + 3 * bb];
            float den = 2.f * tpv + fpv + fnv;
            f1 += (den > 0.f) ? (2.f * tpv) / fmaxf(den, 1.f) : 0.f;
        }
        f1 *= (1.0f / NB);
        out[0] = objT + szT + offT + clsT;
        out[1] = f1;
        out[2] = objT;
        out[3] = szT;
        out[4] = offT;
        out[5] = clsT;
    }
}

extern "C" void kernel_launch(void* const* d_in, const int* in_sizes, int n_in,
                              void* d_out, int out_size, void* d_ws, size_t ws_size,
                              hipStream_t stream) {
    const float* outputs = (const float*)d_in[0];
    const float* labels  = (const float*)d_in[1];
    float* acc = (float*)d_ws;   // 64 stripes x 64 floats = 16 KB

    hipMemsetAsync(acc, 0, NSTR * SACC * sizeof(float), stream);
    yolo_main<<<NBLK, TPB, 0, stream>>>(outputs, labels, acc);
    yolo_fin<<<1, 64, 0, stream>>>(acc, (float*)d_out);
}